// Round 8
// baseline (84.316 us; speedup 1.0000x reference)
//
#include <hip/hip_runtime.h>

// out[b,n,m] = sum_d x1[b,n,d] * x2[b,m,d] + const
// B=4, N=M=4096, D=32, fp32 in/out.
//
// R7: R6 (68.9us) wrote 268MB at only 3.9 TB/s vs 7 TB/s memset rate on the
// same buffer. Cause: scalar-dword stores = 64B segments at 16KB row-stride,
// row-swept before column-swept -> DRAM page scatter. Fix: keep the
// one-MFMA-per-fragment compute (D=32 = one 16x16x32_f16 K-step, absmax
// 0.125 << 0.76), add a WAVE-PRIVATE LDS transpose so stores become
// 4x ds_read_b128 + 4x global_store_dwordx4 per panel, each inst = 4 rows x
// 256B contiguous, advancing column-sequentially. No barriers (wave-private
// buffer; per-wave DS pipe is in-order). LDS ~15us/CU, VALU ~10us, L2
// B-re-reads ~15us -- all under the 38us HBM-write floor.

typedef _Float16 half8 __attribute__((ext_vector_type(8)));
typedef float    f32x4 __attribute__((ext_vector_type(4)));

constexpr int Bv = 4;
constexpr int Nv = 4096;
constexpr int Mv = 4096;
constexpr int Dv = 32;
constexpr int TM = 16;                 // rows per block (one MFMA row-group)
constexpr int COLS_PER_BLOCK = 2048;
constexpr int COLS_PER_WAVE  = 512;
constexpr int NPANEL = COLS_PER_WAVE / 64;   // 8 panels of 64 cols
constexpr int LW = 68;                 // LDS row stride (words): 64 + 4 pad

__global__ __launch_bounds__(256)
void pairwise_mfma_stream(const float* __restrict__ x1,
                          const float* __restrict__ x2,
                          const float* __restrict__ cbias,
                          float* __restrict__ out) {
    __shared__ float tbuf[4][TM][LW];   // wave-private transpose tiles (17.4 KB)

    const int b  = blockIdx.z;
    const int n0 = blockIdx.y * TM;
    const int c0 = blockIdx.x * COLS_PER_BLOCK;
    const int t    = threadIdx.x;       // 0..255
    const int w    = t >> 6;            // wave 0..3
    const int lane = t & 63;
    const int l16  = lane & 15;
    const int lh   = lane >> 4;         // 0..3

    const float* x1b = x1 + (size_t)b * Nv * Dv;
    const float* x2b = x2 + (size_t)b * Mv * Dv;
    const float  cb  = cbias[0];
    float* outb = out + (size_t)b * Nv * Mv;

    // ---- A fragment: 16 rows, loaded ONCE (2 KB contiguous per inst) ----
    // A map (R6-validated): lane -> row l16, k = lh*8 + j
    const float* pa = x1b + (size_t)(n0 + l16) * Dv + lh * 8;
    const f32x4 a0 = *reinterpret_cast<const f32x4*>(pa);
    const f32x4 a1 = *reinterpret_cast<const f32x4*>(pa + 4);
    half8 af;
    af[0] = (_Float16)a0.x; af[1] = (_Float16)a0.y;
    af[2] = (_Float16)a0.z; af[3] = (_Float16)a0.w;
    af[4] = (_Float16)a1.x; af[5] = (_Float16)a1.y;
    af[6] = (_Float16)a1.z; af[7] = (_Float16)a1.w;

    float (*buf)[LW] = tbuf[w];
    const int colw = c0 + w * COLS_PER_WAVE;

    for (int p = 0; p < NPANEL; ++p) {
        const int colp = colw + p * 64;

        // ---- 4 MFMAs: 16 rows x 64 cols ----
        f32x4 acc[4];
        #pragma unroll
        for (int c = 0; c < 4; ++c) {
            // B map (R6-validated): lane -> col l16, k = lh*8 + j
            const float* pb = x2b + (size_t)(colp + c * 16 + l16) * Dv + lh * 8;
            const f32x4 b0 = *reinterpret_cast<const f32x4*>(pb);
            const f32x4 b1 = *reinterpret_cast<const f32x4*>(pb + 4);
            half8 bf;
            bf[0] = (_Float16)b0.x; bf[1] = (_Float16)b0.y;
            bf[2] = (_Float16)b0.z; bf[3] = (_Float16)b0.w;
            bf[4] = (_Float16)b1.x; bf[5] = (_Float16)b1.y;
            bf[6] = (_Float16)b1.z; bf[7] = (_Float16)b1.w;
            f32x4 z = {0.f, 0.f, 0.f, 0.f};
            acc[c] = __builtin_amdgcn_mfma_f32_16x16x32_f16(af, bf, z, 0, 0, 0);
        }

        // ---- transpose via wave-private LDS ----
        // C/D map: row = lh*4 + r, col = c*16 + l16. Writes: 2-way banks (free).
        #pragma unroll
        for (int c = 0; c < 4; ++c)
            #pragma unroll
            for (int r = 0; r < 4; ++r)
                buf[lh * 4 + r][c * 16 + l16] = acc[c][r];

        // ---- read back row-major + store: 4 rows x 256B contiguous per inst ----
        // (per-wave DS pipe is in-order; compiler inserts lgkmcnt before use)
        #pragma unroll
        for (int j = 0; j < 4; ++j) {
            f32x4 v = *reinterpret_cast<const f32x4*>(&buf[j * 4 + lh][l16 * 4]);
            v.x += cb; v.y += cb; v.z += cb; v.w += cb;
            *reinterpret_cast<f32x4*>(
                &outb[(size_t)(n0 + j * 4 + lh) * Mv + colp + l16 * 4]) = v;
        }
    }
}

extern "C" void kernel_launch(void* const* d_in, const int* in_sizes, int n_in,
                              void* d_out, int out_size, void* d_ws, size_t ws_size,
                              hipStream_t stream) {
    const float* x1 = (const float*)d_in[0];   // [B,N,D]
    const float* x2 = (const float*)d_in[1];   // [B,M,D]
    const float* cb = (const float*)d_in[2];   // [1]
    float* out = (float*)d_out;                // [B,N,M]

    dim3 grid(Mv / COLS_PER_BLOCK, Nv / TM, Bv);   // 2 x 256 x 4 = 2048 blocks
    pairwise_mfma_stream<<<grid, 256, 0, stream>>>(x1, x2, cb, out);
}

// Round 9
// 72.777 us; speedup vs baseline: 1.1585x; 1.1585x over previous
//
#include <hip/hip_runtime.h>

// out[b,n,m] = sum_d x1[b,n,d] * x2[b,m,d] + const
// B=4, N=M=4096, D=32, fp32 in/out.
//
// R8: R3/R6/R7 all stall at ~3.2-4.0 TB/s store BW while the harness's own
// fillBufferAligned hits 7 TB/s on the same buffer. Shared defect: scattered
// strided write streams (1KB fragments at 16KB row-stride across a 2MB block
// footprint, from 256 CUs concurrently) -> DRAM page thrash. Fix: emit
// fillBuffer-shaped stores. Per super-iter (256 cols): MFMA stripes -> block
// LDS tile -> barrier -> each wave stores 4 FULL 1KB-contiguous rows via
// nontemporal dwordx4 (one inst = one 1KB run, exactly like fillBuffer).
// Consecutive blocks own consecutive 256KB regions (dispatch-order dense).
// Compute stays one mfma_f32_16x16x32_f16 per fragment (absmax 0.125 << 0.76).

typedef _Float16 half8 __attribute__((ext_vector_type(8)));
typedef float    f32x4 __attribute__((ext_vector_type(4)));

constexpr int Bv = 4;
constexpr int Nv = 4096;
constexpr int Mv = 4096;
constexpr int Dv = 32;
constexpr int ROWS = 16;          // rows per block (one MFMA row-group)
constexpr int CW   = 256;         // cols per super-iter (64 per wave)
constexpr int NIT  = Mv / CW;     // 16 super-iters
constexpr int LW   = CW + 4;      // LDS row stride: 260 words

__global__ __launch_bounds__(256)
void pairwise_mfma_rowstream(const float* __restrict__ x1,
                             const float* __restrict__ x2,
                             const float* __restrict__ cbias,
                             float* __restrict__ out) {
    __shared__ float buf[2][ROWS][LW];   // 33.3 KB -> 4 blocks/CU

    const int b  = blockIdx.y;
    const int n0 = blockIdx.x * ROWS;
    const int t    = threadIdx.x;        // 0..255
    const int w    = t >> 6;             // wave 0..3 -> 64-col stripe
    const int lane = t & 63;
    const int l16  = lane & 15;
    const int lh   = lane >> 4;          // 0..3

    const float* x1b = x1 + (size_t)b * Nv * Dv;
    const float* x2b = x2 + (size_t)b * Mv * Dv;
    const float  cb  = cbias[0];
    float* outb = out + (size_t)b * Nv * Mv;

    // ---- A fragment: 16 rows, loaded once (lane -> row l16, k lh*8+j) ----
    const float* pa = x1b + (size_t)(n0 + l16) * Dv + lh * 8;
    const f32x4 a0 = *reinterpret_cast<const f32x4*>(pa);
    const f32x4 a1 = *reinterpret_cast<const f32x4*>(pa + 4);
    half8 af;
    af[0] = (_Float16)a0.x; af[1] = (_Float16)a0.y;
    af[2] = (_Float16)a0.z; af[3] = (_Float16)a0.w;
    af[4] = (_Float16)a1.x; af[5] = (_Float16)a1.y;
    af[6] = (_Float16)a1.z; af[7] = (_Float16)a1.w;

    for (int q = 0; q < NIT; ++q) {
        const int cur  = q & 1;
        const int colq = q * CW;
        const int pcol = colq + w * 64;

        // ---- 4 MFMAs: wave's 16x64 stripe ----
        f32x4 acc[4];
        #pragma unroll
        for (int c = 0; c < 4; ++c) {
            const float* pb = x2b + (size_t)(pcol + c * 16 + l16) * Dv + lh * 8;
            const f32x4 b0 = *reinterpret_cast<const f32x4*>(pb);
            const f32x4 b1 = *reinterpret_cast<const f32x4*>(pb + 4);
            half8 bf;
            bf[0] = (_Float16)b0.x; bf[1] = (_Float16)b0.y;
            bf[2] = (_Float16)b0.z; bf[3] = (_Float16)b0.w;
            bf[4] = (_Float16)b1.x; bf[5] = (_Float16)b1.y;
            bf[6] = (_Float16)b1.z; bf[7] = (_Float16)b1.w;
            f32x4 z = {0.f, 0.f, 0.f, 0.f};
            acc[c] = __builtin_amdgcn_mfma_f32_16x16x32_f16(af, bf, z, 0, 0, 0);
        }

        // ---- scatter stripe into block tile (C/D: row lh*4+r, col c*16+l16) ----
        // banks: (lh*16 + l16) % 32 -> 2-way max (free)
        #pragma unroll
        for (int c = 0; c < 4; ++c)
            #pragma unroll
            for (int r = 0; r < 4; ++r)
                buf[cur][lh * 4 + r][w * 64 + c * 16 + l16] = acc[c][r];

        __syncthreads();   // tile complete (single barrier/iter; double-buffered)

        // ---- readback + store: wave w owns rows w*4..w*4+3 ----
        // per inst: 64 lanes x 16B = 1KB CONTIGUOUS of one row (fillBuffer-shaped)
        #pragma unroll
        for (int j = 0; j < 4; ++j) {
            const int row = w * 4 + j;
            f32x4 v = *reinterpret_cast<const f32x4*>(&buf[cur][row][lane * 4]);
            v.x += cb; v.y += cb; v.z += cb; v.w += cb;
            __builtin_nontemporal_store(
                v, reinterpret_cast<f32x4*>(
                       &outb[(size_t)(n0 + row) * Mv + colq + lane * 4]));
        }
    }
}

extern "C" void kernel_launch(void* const* d_in, const int* in_sizes, int n_in,
                              void* d_out, int out_size, void* d_ws, size_t ws_size,
                              hipStream_t stream) {
    const float* x1 = (const float*)d_in[0];   // [B,N,D]
    const float* x2 = (const float*)d_in[1];   // [B,M,D]
    const float* cb = (const float*)d_in[2];   // [1]
    float* out = (float*)d_out;                // [B,N,M]

    dim3 grid(Nv / ROWS, Bv, 1);               // 256 x 4 = 1024 blocks, 4/CU
    pairwise_mfma_rowstream<<<grid, 256, 0, stream>>>(x1, x2, cb, out);
}